// Round 15
// baseline (650.643 us; speedup 1.0000x reference)
//
#include <hip/hip_runtime.h>
#include <hip/hip_fp16.h>

// Hyperbolic GCN layer, c = 1.0
// x [N,D] f32, W [D,D] f32, edge_vals [E] f32, rows [E] i32, cols [E] i32 -> out [N,D] f32
//
// Algebraic note (verified vs reference): with sc=1,
//   logmap0(mobius_matvec(W,x)) = (atanh(||x||)/||x||) * (W x)      [atanh∘tanh cancels]
//   relu(logmap0(expmap0(s)))   = relu(s)                           [logmap0∘expmap0 = id]
#define NN 100000
#define DD 64
#define EE 1600000
#define NB 512          // node buckets == sort chunks
#define NPB 196         // nodes per bucket (NB*NPB = 100352 >= NN)
#define CHUNK 3125      // edges per chunk (CHUNK * NB == EE)
#define ASTRIDE 65      // accum row stride (odd -> bank spread; 196*65*4 = 50,960 B)

typedef _Float16 half8 __attribute__((ext_vector_type(8)));
typedef float floatx4 __attribute__((ext_vector_type(4)));

__device__ __forceinline__ float frcp(float x) { return __builtin_amdgcn_rcpf(x); }

__device__ __forceinline__ float fast_tanh(float x) {           // x >= 0 here
    float t = __expf(2.0f * x);
    return (t - 1.0f) * frcp(t + 1.0f);
}
__device__ __forceinline__ float fast_atanh(float x) {
    const float CLIP = 1.0f - 1e-7f;
    x = fminf(fmaxf(x, -CLIP), CLIP);
    return 0.5f * __logf((1.0f + x) * frcp(1.0f - x));
}
__device__ __forceinline__ float wave_reduce_sum(float v) {
    #pragma unroll
    for (int m = 32; m > 0; m >>= 1) v += __shfl_xor(v, m, 64);
    return v;
}
__device__ __forceinline__ float lo16f(unsigned u) {
    return __half2float(__ushort_as_half((unsigned short)(u & 0xFFFFu)));
}
__device__ __forceinline__ float hi16f(unsigned u) {
    return __half2float(__ushort_as_half((unsigned short)(u >> 16)));
}

// ---- Stage 1 (MFMA) + per-chunk bucket counts (round-12 proven form) ----
__global__ __launch_bounds__(1024) void linear_count_kernel(
    const float* __restrict__ x, const float* __restrict__ W,
    const int* __restrict__ rows,
    __half* __restrict__ hidden, int* __restrict__ cnt) {
    __shared__ _Float16 Wh[64 * 80];   // stride 80 halves keeps b128 aligned
    __shared__ int h[NB];
    const int t = threadIdx.x;

    if (t < NB) h[t] = 0;
    for (int i = t; i < 64 * 64; i += 1024)
        Wh[(i >> 6) * 80 + (i & 63)] = (_Float16)W[i];
    __syncthreads();

    {   // histogram this chunk (LDS atomics only)
        const int e0 = blockIdx.x * CHUNK;
        for (int i = t; i < CHUNK; i += 1024)
            atomicAdd(&h[(unsigned)rows[e0 + i] / NPB], 1);
    }

    const int lane = t & 63;
    const int wv   = t >> 6;             // waves 0..12 do MFMA (13*16=208 nodes)
    if (wv < 13) {
        const int q    = lane >> 4;
        const int c    = lane & 15;
        const int node = blockIdx.x * NPB + wv * 16 + c;
        const int node_ld = (node < NN) ? node : (NN - 1);

        const float MIN_NORM = 1e-15f;
        const float4* xr = (const float4*)(x + node_ld * 64);
        float4 b0a = xr[q * 2];
        float4 b0b = xr[q * 2 + 1];
        float4 b1a = xr[8 + q * 2];
        float4 b1b = xr[8 + q * 2 + 1];

        float xpart = b0a.x*b0a.x + b0a.y*b0a.y + b0a.z*b0a.z + b0a.w*b0a.w
                    + b0b.x*b0b.x + b0b.y*b0b.y + b0b.z*b0b.z + b0b.w*b0b.w
                    + b1a.x*b1a.x + b1a.y*b1a.y + b1a.z*b1a.z + b1a.w*b1a.w
                    + b1b.x*b1b.x + b1b.y*b1b.y + b1b.z*b1b.z + b1b.w*b1b.w;
        xpart += __shfl_xor(xpart, 16, 64);
        xpart += __shfl_xor(xpart, 32, 64);
        float x_n = fmaxf(sqrtf(xpart), MIN_NORM);

        half8 bf0, bf1;
        bf0[0]=(_Float16)b0a.x; bf0[1]=(_Float16)b0a.y; bf0[2]=(_Float16)b0a.z; bf0[3]=(_Float16)b0a.w;
        bf0[4]=(_Float16)b0b.x; bf0[5]=(_Float16)b0b.y; bf0[6]=(_Float16)b0b.z; bf0[7]=(_Float16)b0b.w;
        bf1[0]=(_Float16)b1a.x; bf1[1]=(_Float16)b1a.y; bf1[2]=(_Float16)b1a.z; bf1[3]=(_Float16)b1a.w;
        bf1[4]=(_Float16)b1b.x; bf1[5]=(_Float16)b1b.y; bf1[6]=(_Float16)b1b.z; bf1[7]=(_Float16)b1b.w;

        floatx4 acc[4];
        #pragma unroll
        for (int tt = 0; tt < 4; ++tt) {
            const half8* a0 = (const half8*)&Wh[(16 * tt + c) * 80 + q * 8];
            const half8* a1 = (const half8*)&Wh[(16 * tt + c) * 80 + 32 + q * 8];
            floatx4 z = {0.f, 0.f, 0.f, 0.f};
            z = __builtin_amdgcn_mfma_f32_16x16x32_f16(a0[0], bf0, z, 0, 0, 0);
            z = __builtin_amdgcn_mfma_f32_16x16x32_f16(a1[0], bf1, z, 0, 0, 0);
            acc[tt] = z;
        }

        float hscale = fast_atanh(x_n) * frcp(x_n);

        if (node < NN) {
            #pragma unroll
            for (int tt = 0; tt < 4; ++tt) {
                __half2 lo = __floats2half2_rn(acc[tt][0] * hscale, acc[tt][1] * hscale);
                __half2 hi = __floats2half2_rn(acc[tt][2] * hscale, acc[tt][3] * hscale);
                uint2 pkt;
                pkt.x = *(unsigned*)&lo;
                pkt.y = *(unsigned*)&hi;
                ((uint2*)hidden)[node * 16 + tt * 4 + q] = pkt;
            }
        }
    }
    __syncthreads();
    if (t < NB) cnt[blockIdx.x * NB + t] = h[t];   // coalesced row write
}

// ---- Per-bucket exclusive scan over chunk counts -> woff + bucket totals ----
__global__ __launch_bounds__(512) void offset_kernel(const int* __restrict__ cnt,
                                                     int* __restrict__ woff,
                                                     int* __restrict__ gcount) {
    const int lane = threadIdx.x & 63;
    const int b    = blockIdx.x * 8 + (threadIdx.x >> 6);   // bucket
    int c[8]; int sum = 0;
    #pragma unroll
    for (int k = 0; k < 8; ++k) { c[k] = cnt[(lane * 8 + k) * NB + b]; sum += c[k]; }
    int pre = sum;
    #pragma unroll
    for (int m = 1; m < 64; m <<= 1) {
        int u = __shfl_up(pre, m, 64);
        if (lane >= m) pre += u;
    }
    int run = pre - sum;
    #pragma unroll
    for (int k = 0; k < 8; ++k) { woff[(lane * 8 + k) * NB + b] = run; run += c[k]; }
    if (lane == 63) gcount[b] = run;   // bucket total
}

// ---- Exclusive scan over 512 bucket totals: single wave ----
__global__ __launch_bounds__(64) void scan_kernel(const int* __restrict__ gcount,
                                                  int* __restrict__ bbase) {
    const int lane = threadIdx.x;
    int c[8]; int sum = 0;
    #pragma unroll
    for (int k = 0; k < 8; ++k) { c[k] = gcount[lane * 8 + k]; sum += c[k]; }
    int pre = sum;
    #pragma unroll
    for (int m = 1; m < 64; m <<= 1) {
        int u = __shfl_up(pre, m, 64);
        if (lane >= m) pre += u;
    }
    int run = pre - sum;
    #pragma unroll
    for (int k = 0; k < 8; ++k) { bbase[lane * 8 + k] = run; run += c[k]; }
    if (lane == 63) bbase[NB] = run;   // == EE
}

// ---- Local counting sort + coalesced scatter (round-12 proven, int2 records).
// payload: word0 = rl<<24 | col*128 (byte offset into fp16 hidden rows), word1 = val fp32
__global__ __launch_bounds__(1024) void sort_scatter_kernel(
    const int* __restrict__ rows, const int* __restrict__ cols,
    const float* __restrict__ ev, const int* __restrict__ cnt,
    const int* __restrict__ woff, const int* __restrict__ bbase,
    int2* __restrict__ csr) {
    __shared__ int cur[NB];
    __shared__ int delta[NB];
    __shared__ int2 sorted[CHUNK];
    __shared__ unsigned short bid[CHUNK];
    const int t  = threadIdx.x;
    const int e0 = blockIdx.x * CHUNK;

    if (t < 64) {
        const int lane = t;
        int c[8]; int sum = 0;
        #pragma unroll
        for (int k = 0; k < 8; ++k) { c[k] = cnt[blockIdx.x * NB + lane * 8 + k]; sum += c[k]; }
        int pre = sum;
        #pragma unroll
        for (int m = 1; m < 64; m <<= 1) {
            int u = __shfl_up(pre, m, 64);
            if (lane >= m) pre += u;
        }
        int run = pre - sum;
        #pragma unroll
        for (int k = 0; k < 8; ++k) {
            int b = lane * 8 + k;
            cur[b]   = run;                                        // LDS scatter cursor
            delta[b] = bbase[b] + woff[blockIdx.x * NB + b] - run; // LDS pos -> global
            run += c[k];
        }
    }
    __syncthreads();
    for (int i = t; i < CHUNK; i += 1024) {
        unsigned r = (unsigned)rows[e0 + i];
        unsigned c = (unsigned)cols[e0 + i];
        float v = ev[e0 + i];
        unsigned b  = r / NPB;
        unsigned rl = r - b * NPB;
        int idx = atomicAdd(&cur[b], 1);
        sorted[idx] = make_int2((int)((rl << 24) | (c << 7)), __float_as_int(v));
        bid[idx] = (unsigned short)b;
    }
    __syncthreads();
    for (int i = t; i < CHUNK; i += 1024) {
        int2 eV = sorted[i];
        csr[delta[bid[i]] + i] = eV;
    }
}

// ---- NEW: direct quarter-wave accumulation into padded LDS accumulator.
//      No in-block sort, no hist, single csr read. One block per bucket.
//      Per edge: 1/4 record load + 1/4 gather + 4 ds_add_f32 (stride-65 rows). ----
__global__ __launch_bounds__(1024) void accum_gather_kernel(
    const __half* __restrict__ hidden, const int2* __restrict__ csr,
    const int* __restrict__ bbase, float* __restrict__ out) {
    __shared__ float accum[NPB * ASTRIDE];   // 50,960 B
    const int t  = threadIdx.x;
    const int b  = blockIdx.x;
    const int lo = bbase[b];
    const int cnt = bbase[b + 1] - lo;

    for (int i = t; i < NPB * ASTRIDE; i += 1024) accum[i] = 0.0f;
    __syncthreads();

    const int lane = t & 63;
    const int wv   = t >> 6;               // 0..15
    const int g    = lane >> 4;            // edge-in-group
    const int l    = lane & 15;            // feature quarter: features 4l..4l+3
    const int l8   = l * 8;
    const char* __restrict__ hidc = (const char*)hidden;

    // wave wv owns 8-edge tiles starting at wv*8, stride 16*8
    int i = wv * 8;
    for (; i + 8 <= cnt; i += 128) {
        int2 dA = csr[lo + i + g];
        int2 dB = csr[lo + i + 4 + g];
        unsigned oA = ((unsigned)dA.x & 0xFFFFFFu) + l8;
        unsigned oB = ((unsigned)dB.x & 0xFFFFFFu) + l8;
        uint2 hA = *(const uint2*)(hidc + oA);
        uint2 hB = *(const uint2*)(hidc + oB);
        float vA = __int_as_float(dA.y);
        float vB = __int_as_float(dB.y);
        float* rA = &accum[(((unsigned)dA.x) >> 24) * ASTRIDE + l * 4];
        float* rB = &accum[(((unsigned)dB.x) >> 24) * ASTRIDE + l * 4];
        atomicAdd(&rA[0], vA * lo16f(hA.x));
        atomicAdd(&rA[1], vA * hi16f(hA.x));
        atomicAdd(&rA[2], vA * lo16f(hA.y));
        atomicAdd(&rA[3], vA * hi16f(hA.y));
        atomicAdd(&rB[0], vB * lo16f(hB.x));
        atomicAdd(&rB[1], vB * hi16f(hB.x));
        atomicAdd(&rB[2], vB * lo16f(hB.y));
        atomicAdd(&rB[3], vB * hi16f(hB.y));
    }
    for (; i < cnt; i += 4) {              // masked tail groups (exactly one wave, <=2 iters)
        int idx = i + g;
        bool ok = idx < cnt;
        int2 d = csr[lo + (ok ? idx : cnt - 1)];
        float v = ok ? __int_as_float(d.y) : 0.0f;   // adding 0 is a value-level no-op
        unsigned o = ((unsigned)d.x & 0xFFFFFFu) + l8;
        uint2 h = *(const uint2*)(hidc + o);
        float* r = &accum[(((unsigned)d.x) >> 24) * ASTRIDE + l * 4];
        atomicAdd(&r[0], v * lo16f(h.x));
        atomicAdd(&r[1], v * hi16f(h.x));
        atomicAdd(&r[2], v * lo16f(h.y));
        atomicAdd(&r[3], v * hi16f(h.y));
    }
    __syncthreads();

    // epilogue: wave per node, lane = feature. out = proj(expmap0(relu(support)))
    const float MIN_NORM = 1e-15f;
    const float MAX_N = 1.0f - 1e-5f;
    for (int n = wv; n < NPB; n += 16) {
        float s  = accum[n * ASTRIDE + lane];
        float xt = fmaxf(s, 0.0f);
        float xt_n = fmaxf(sqrtf(wave_reduce_sum(xt * xt)), MIN_NORM);
        float txt  = fast_tanh(xt_n);                 // = ||out||
        float s3   = txt * frcp(xt_n);
        if (txt > MAX_N) s3 = MAX_N * frcp(xt_n);     // proj (dormant, kept)
        int gn = b * NPB + n;
        if (gn < NN) out[gn * DD + lane] = xt * s3;
    }
}

extern "C" void kernel_launch(void* const* d_in, const int* in_sizes, int n_in,
                              void* d_out, int out_size, void* d_ws, size_t ws_size,
                              hipStream_t stream) {
    const float* x    = (const float*)d_in[0];
    const float* W    = (const float*)d_in[1];
    const float* ev   = (const float*)d_in[2];
    const int*   rows = (const int*)d_in[3];
    const int*   cols = (const int*)d_in[4];
    float* out = (float*)d_out;

    char* ws = (char*)d_ws;
    __half* hidden = (__half*)ws;                 // 12,800,000 B
    int2*   csr    = (int2*)(ws + 12800000);      // 12,800,000 B
    int*    cnt    = (int*)(ws + 25600000);       //  1,048,576 B
    int*    woff   = (int*)(ws + 26648576);       //  1,048,576 B
    int*    gcount = (int*)(ws + 27697152);       //      2,048 B
    int*    bbase  = (int*)(ws + 27699200);       //      2,052 B
                                                  // total ~27.7 MB

    linear_count_kernel<<<NB, 1024, 0, stream>>>(x, W, rows, hidden, cnt);
    offset_kernel<<<NB / 8, 512, 0, stream>>>(cnt, woff, gcount);
    scan_kernel<<<1, 64, 0, stream>>>(gcount, bbase);
    sort_scatter_kernel<<<NB, 1024, 0, stream>>>(rows, cols, ev, cnt, woff, bbase, csr);
    accum_gather_kernel<<<NB, 1024, 0, stream>>>(hidden, csr, bbase, out);
}

// Round 16
// 149.240 us; speedup vs baseline: 4.3597x; 4.3597x over previous
//
#include <hip/hip_runtime.h>
#include <hip/hip_fp16.h>

// Hyperbolic GCN layer, c = 1.0
// x [N,D] f32, W [D,D] f32, edge_vals [E] f32, rows [E] i32, cols [E] i32 -> out [N,D] f32
//
// Algebraic note (verified vs reference): with sc=1,
//   logmap0(mobius_matvec(W,x)) = (atanh(||x||)/||x||) * (W x)      [atanh∘tanh cancels]
//   relu(logmap0(expmap0(s)))   = relu(s)                           [logmap0∘expmap0 = id]
//
// Structure (round-12 configuration, best verified at 149.6 us):
//   linear_count (MFMA matvec + chunk histograms) -> offset (per-bucket scan over
//   chunks) -> scan (bucket bases) -> sort_scatter (LDS counting sort, deterministic
//   offsets, no global atomics) -> sortgather (per-bucket node sort in LDS +
//   quarter-wave register gather + fused epilogue).
// Forbidden patterns (measured): scattered per-lane LDS float atomics (R3: 557us,
// R15: 538us); serial chained global atomics for range reservation (R8: 86us stall).
#define NN 100000
#define DD 64
#define EE 1600000
#define NB 512          // node buckets == sort chunks
#define NPB 196         // nodes per bucket (NB*NPB = 100352 >= NN)
#define CHUNK 3125      // edges per chunk (CHUNK * NB == EE)
#define CAP 3520        // per-bucket LDS capacity (mean 3125, sigma ~56 -> +7 sigma)

typedef _Float16 half8 __attribute__((ext_vector_type(8)));
typedef float floatx4 __attribute__((ext_vector_type(4)));

__device__ __forceinline__ float frcp(float x) { return __builtin_amdgcn_rcpf(x); }

__device__ __forceinline__ float fast_tanh(float x) {           // x >= 0 here
    float t = __expf(2.0f * x);
    return (t - 1.0f) * frcp(t + 1.0f);
}
__device__ __forceinline__ float fast_atanh(float x) {
    const float CLIP = 1.0f - 1e-7f;
    x = fminf(fmaxf(x, -CLIP), CLIP);
    return 0.5f * __logf((1.0f + x) * frcp(1.0f - x));
}
__device__ __forceinline__ float group16_reduce_sum(float v) {
    #pragma unroll
    for (int m = 8; m > 0; m >>= 1) v += __shfl_xor(v, m, 16);
    return v;
}
__device__ __forceinline__ float lo16f(unsigned u) {
    return __half2float(__ushort_as_half((unsigned short)(u & 0xFFFFu)));
}
__device__ __forceinline__ float hi16f(unsigned u) {
    return __half2float(__ushort_as_half((unsigned short)(u >> 16)));
}

// ---- Stage 1 (MFMA) + per-chunk bucket counts ----
__global__ __launch_bounds__(1024) void linear_count_kernel(
    const float* __restrict__ x, const float* __restrict__ W,
    const int* __restrict__ rows,
    __half* __restrict__ hidden, int* __restrict__ cnt) {
    __shared__ _Float16 Wh[64 * 80];   // stride 80 halves keeps b128 aligned
    __shared__ int h[NB];
    const int t = threadIdx.x;

    if (t < NB) h[t] = 0;
    for (int i = t; i < 64 * 64; i += 1024)
        Wh[(i >> 6) * 80 + (i & 63)] = (_Float16)W[i];
    __syncthreads();

    {   // histogram this chunk (LDS atomics on 512 int counters only)
        const int e0 = blockIdx.x * CHUNK;
        for (int i = t; i < CHUNK; i += 1024)
            atomicAdd(&h[(unsigned)rows[e0 + i] / NPB], 1);
    }

    const int lane = t & 63;
    const int wv   = t >> 6;             // waves 0..12 do MFMA (13*16=208 nodes)
    if (wv < 13) {
        const int q    = lane >> 4;
        const int c    = lane & 15;
        const int node = blockIdx.x * NPB + wv * 16 + c;
        const int node_ld = (node < NN) ? node : (NN - 1);

        const float MIN_NORM = 1e-15f;
        const float4* xr = (const float4*)(x + node_ld * 64);
        float4 b0a = xr[q * 2];
        float4 b0b = xr[q * 2 + 1];
        float4 b1a = xr[8 + q * 2];
        float4 b1b = xr[8 + q * 2 + 1];

        float xpart = b0a.x*b0a.x + b0a.y*b0a.y + b0a.z*b0a.z + b0a.w*b0a.w
                    + b0b.x*b0b.x + b0b.y*b0b.y + b0b.z*b0b.z + b0b.w*b0b.w
                    + b1a.x*b1a.x + b1a.y*b1a.y + b1a.z*b1a.z + b1a.w*b1a.w
                    + b1b.x*b1b.x + b1b.y*b1b.y + b1b.z*b1b.z + b1b.w*b1b.w;
        xpart += __shfl_xor(xpart, 16, 64);
        xpart += __shfl_xor(xpart, 32, 64);
        float x_n = fmaxf(sqrtf(xpart), MIN_NORM);

        half8 bf0, bf1;
        bf0[0]=(_Float16)b0a.x; bf0[1]=(_Float16)b0a.y; bf0[2]=(_Float16)b0a.z; bf0[3]=(_Float16)b0a.w;
        bf0[4]=(_Float16)b0b.x; bf0[5]=(_Float16)b0b.y; bf0[6]=(_Float16)b0b.z; bf0[7]=(_Float16)b0b.w;
        bf1[0]=(_Float16)b1a.x; bf1[1]=(_Float16)b1a.y; bf1[2]=(_Float16)b1a.z; bf1[3]=(_Float16)b1a.w;
        bf1[4]=(_Float16)b1b.x; bf1[5]=(_Float16)b1b.y; bf1[6]=(_Float16)b1b.z; bf1[7]=(_Float16)b1b.w;

        floatx4 acc[4];
        #pragma unroll
        for (int tt = 0; tt < 4; ++tt) {
            const half8* a0 = (const half8*)&Wh[(16 * tt + c) * 80 + q * 8];
            const half8* a1 = (const half8*)&Wh[(16 * tt + c) * 80 + 32 + q * 8];
            floatx4 z = {0.f, 0.f, 0.f, 0.f};
            z = __builtin_amdgcn_mfma_f32_16x16x32_f16(a0[0], bf0, z, 0, 0, 0);
            z = __builtin_amdgcn_mfma_f32_16x16x32_f16(a1[0], bf1, z, 0, 0, 0);
            acc[tt] = z;
        }

        float hscale = fast_atanh(x_n) * frcp(x_n);

        if (node < NN) {
            #pragma unroll
            for (int tt = 0; tt < 4; ++tt) {
                __half2 lo = __floats2half2_rn(acc[tt][0] * hscale, acc[tt][1] * hscale);
                __half2 hi = __floats2half2_rn(acc[tt][2] * hscale, acc[tt][3] * hscale);
                uint2 pkt;
                pkt.x = *(unsigned*)&lo;
                pkt.y = *(unsigned*)&hi;
                ((uint2*)hidden)[node * 16 + tt * 4 + q] = pkt;
            }
        }
    }
    __syncthreads();
    if (t < NB) cnt[blockIdx.x * NB + t] = h[t];   // coalesced row write
}

// ---- Per-bucket exclusive scan over chunk counts -> woff + bucket totals ----
__global__ __launch_bounds__(512) void offset_kernel(const int* __restrict__ cnt,
                                                     int* __restrict__ woff,
                                                     int* __restrict__ gcount) {
    const int lane = threadIdx.x & 63;
    const int b    = blockIdx.x * 8 + (threadIdx.x >> 6);   // bucket
    int c[8]; int sum = 0;
    #pragma unroll
    for (int k = 0; k < 8; ++k) { c[k] = cnt[(lane * 8 + k) * NB + b]; sum += c[k]; }
    int pre = sum;
    #pragma unroll
    for (int m = 1; m < 64; m <<= 1) {
        int u = __shfl_up(pre, m, 64);
        if (lane >= m) pre += u;
    }
    int run = pre - sum;
    #pragma unroll
    for (int k = 0; k < 8; ++k) { woff[(lane * 8 + k) * NB + b] = run; run += c[k]; }
    if (lane == 63) gcount[b] = run;   // bucket total
}

// ---- Exclusive scan over 512 bucket totals: single wave ----
__global__ __launch_bounds__(64) void scan_kernel(const int* __restrict__ gcount,
                                                  int* __restrict__ bbase) {
    const int lane = threadIdx.x;
    int c[8]; int sum = 0;
    #pragma unroll
    for (int k = 0; k < 8; ++k) { c[k] = gcount[lane * 8 + k]; sum += c[k]; }
    int pre = sum;
    #pragma unroll
    for (int m = 1; m < 64; m <<= 1) {
        int u = __shfl_up(pre, m, 64);
        if (lane >= m) pre += u;
    }
    int run = pre - sum;
    #pragma unroll
    for (int k = 0; k < 8; ++k) { bbase[lane * 8 + k] = run; run += c[k]; }
    if (lane == 63) bbase[NB] = run;   // == EE
}

// ---- Local counting sort + coalesced scatter. Counts precomputed; deterministic
//      offsets, no global atomics.
// payload: word0 = rl<<24 | col*128 (byte offset into fp16 hidden rows), word1 = val fp32
__global__ __launch_bounds__(1024) void sort_scatter_kernel(
    const int* __restrict__ rows, const int* __restrict__ cols,
    const float* __restrict__ ev, const int* __restrict__ cnt,
    const int* __restrict__ woff, const int* __restrict__ bbase,
    int2* __restrict__ csr) {
    __shared__ int cur[NB];
    __shared__ int delta[NB];
    __shared__ int2 sorted[CHUNK];
    __shared__ unsigned short bid[CHUNK];
    const int t  = threadIdx.x;
    const int e0 = blockIdx.x * CHUNK;

    if (t < 64) {
        const int lane = t;
        int c[8]; int sum = 0;
        #pragma unroll
        for (int k = 0; k < 8; ++k) { c[k] = cnt[blockIdx.x * NB + lane * 8 + k]; sum += c[k]; }
        int pre = sum;
        #pragma unroll
        for (int m = 1; m < 64; m <<= 1) {
            int u = __shfl_up(pre, m, 64);
            if (lane >= m) pre += u;
        }
        int run = pre - sum;
        #pragma unroll
        for (int k = 0; k < 8; ++k) {
            int b = lane * 8 + k;
            cur[b]   = run;                                        // LDS scatter cursor
            delta[b] = bbase[b] + woff[blockIdx.x * NB + b] - run; // LDS pos -> global
            run += c[k];
        }
    }
    __syncthreads();
    for (int i = t; i < CHUNK; i += 1024) {
        unsigned r = (unsigned)rows[e0 + i];
        unsigned c = (unsigned)cols[e0 + i];
        float v = ev[e0 + i];
        unsigned b  = r / NPB;
        unsigned rl = r - b * NPB;
        int idx = atomicAdd(&cur[b], 1);
        sorted[idx] = make_int2((int)((rl << 24) | (c << 7)), __float_as_int(v));
        bid[idx] = (unsigned short)b;
    }
    __syncthreads();
    for (int i = t; i < CHUNK; i += 1024) {
        int2 eV = sorted[i];
        csr[delta[bid[i]] + i] = eV;
    }
}

// ---- Fused: per-bucket node counting-sort in LDS + quarter-wave register gather
//      + epilogue out = proj(expmap0(relu(support))). ----
__global__ __launch_bounds__(1024) void sortgather_kernel(
    const __half* __restrict__ hidden, const int2* __restrict__ csr,
    const int* __restrict__ bbase, float* __restrict__ out) {
    __shared__ int2 srt[CAP];          // 28,160 B, node-sorted descriptors
    __shared__ int cnt_a[NPB];
    __shared__ int start[NPB];
    __shared__ int cur[NPB];
    const int t  = threadIdx.x;
    const int b  = blockIdx.x;
    const int lo = bbase[b];
    int cnt = bbase[b + 1] - lo;
    if (cnt > CAP) cnt = CAP;          // statistically unreachable guard

    if (t < NPB) cnt_a[t] = 0;
    __syncthreads();
    for (int i = t; i < cnt; i += 1024)
        atomicAdd(&cnt_a[((unsigned)csr[lo + i].x) >> 24], 1);
    __syncthreads();
    if (t < 64) {
        const int lane = t;
        int c[4]; int sum = 0;
        #pragma unroll
        for (int k = 0; k < 4; ++k) {
            int bb = lane * 4 + k;
            c[k] = (bb < NPB) ? cnt_a[bb] : 0;
            sum += c[k];
        }
        int pre = sum;
        #pragma unroll
        for (int m = 1; m < 64; m <<= 1) {
            int u = __shfl_up(pre, m, 64);
            if (lane >= m) pre += u;
        }
        int run = pre - sum;
        #pragma unroll
        for (int k = 0; k < 4; ++k) {
            int bb = lane * 4 + k;
            if (bb < NPB) { start[bb] = run; cur[bb] = run; run += c[k]; }
        }
    }
    __syncthreads();
    for (int i = t; i < cnt; i += 1024) {
        int2 e = csr[lo + i];
        int rl = ((unsigned)e.x) >> 24;
        int p  = atomicAdd(&cur[rl], 1);
        srt[p] = e;
    }
    __syncthreads();

    const int lane = t & 63;
    const int wv   = t >> 6;               // 0..15
    const int g    = lane >> 4;
    const int l8   = (lane & 15) * 8;
    const char* __restrict__ hidc = (const char*)hidden;
    const float MIN_NORM = 1e-15f;
    const float MAX_N = 1.0f - 1e-5f;

    for (int n = wv; n < NPB; n += 16) {
        int i   = start[n];
        int rhi = i + cnt_a[n];
        float ax = 0.f, ay = 0.f, az = 0.f, aw = 0.f;

        for (; i + 8 <= rhi; i += 8) {           // 2 groups of 4 edges
            int2 dA = srt[i + g];
            int2 dB = srt[i + 4 + g];
            unsigned oA = (((unsigned)dA.x) & 0xFFFFFFu) + l8;
            unsigned oB = (((unsigned)dB.x) & 0xFFFFFFu) + l8;
            uint2 hA = *(const uint2*)(hidc + oA);
            uint2 hB = *(const uint2*)(hidc + oB);
            float vA = __int_as_float(dA.y);
            float vB = __int_as_float(dB.y);
            ax = fmaf(vA, lo16f(hA.x), ax);
            ay = fmaf(vA, hi16f(hA.x), ay);
            az = fmaf(vA, lo16f(hA.y), az);
            aw = fmaf(vA, hi16f(hA.y), aw);
            ax = fmaf(vB, lo16f(hB.x), ax);
            ay = fmaf(vB, hi16f(hB.x), ay);
            az = fmaf(vB, lo16f(hB.y), az);
            aw = fmaf(vB, hi16f(hB.y), aw);
        }
        for (; i < rhi; i += 4) {                // masked 4-edge groups (<=2 iters)
            int idx = i + g;
            int2 d = srt[(idx < rhi) ? idx : (rhi - 1)];
            float v = (idx < rhi) ? __int_as_float(d.y) : 0.0f;
            unsigned o = (((unsigned)d.x) & 0xFFFFFFu) + l8;
            uint2 h = *(const uint2*)(hidc + o);
            ax = fmaf(v, lo16f(h.x), ax);
            ay = fmaf(v, hi16f(h.x), ay);
            az = fmaf(v, lo16f(h.y), az);
            aw = fmaf(v, hi16f(h.y), aw);
        }

        ax += __shfl_xor(ax, 16, 64); ax += __shfl_xor(ax, 32, 64);
        ay += __shfl_xor(ay, 16, 64); ay += __shfl_xor(ay, 32, 64);
        az += __shfl_xor(az, 16, 64); az += __shfl_xor(az, 32, 64);
        aw += __shfl_xor(aw, 16, 64); aw += __shfl_xor(aw, 32, 64);

        float xx = fmaxf(ax, 0.f), xy = fmaxf(ay, 0.f);
        float xz = fmaxf(az, 0.f), xw = fmaxf(aw, 0.f);

        float part = xx*xx + xy*xy + xz*xz + xw*xw;
        float xt_n = fmaxf(sqrtf(group16_reduce_sum(part)), MIN_NORM);
        float txt  = fast_tanh(xt_n);                 // = ||out||
        float s3   = txt * frcp(xt_n);
        if (txt > MAX_N) s3 = MAX_N * frcp(xt_n);     // proj (dormant, kept)
        float ox = xx*s3, oy = xy*s3, oz = xz*s3, ow = xw*s3;

        int gn = b * NPB + n;
        if (g == 0 && gn < NN) {
            float4 o4 = make_float4(ox, oy, oz, ow);
            *(float4*)(out + gn * DD + (lane & 15) * 4) = o4;
        }
    }
}

extern "C" void kernel_launch(void* const* d_in, const int* in_sizes, int n_in,
                              void* d_out, int out_size, void* d_ws, size_t ws_size,
                              hipStream_t stream) {
    const float* x    = (const float*)d_in[0];
    const float* W    = (const float*)d_in[1];
    const float* ev   = (const float*)d_in[2];
    const int*   rows = (const int*)d_in[3];
    const int*   cols = (const int*)d_in[4];
    float* out = (float*)d_out;

    char* ws = (char*)d_ws;
    __half* hidden = (__half*)ws;                 // 12,800,000 B
    int2*   csr    = (int2*)(ws + 12800000);      // 12,800,000 B
    int*    cnt    = (int*)(ws + 25600000);       //  1,048,576 B (512x512 counts)
    int*    woff   = (int*)(ws + 26648576);       //  1,048,576 B (per-chunk bucket offsets)
    int*    gcount = (int*)(ws + 27697152);       //      2,048 B
    int*    bbase  = (int*)(ws + 27699200);       //      2,052 B
                                                  // total ~27.7 MB

    linear_count_kernel<<<NB, 1024, 0, stream>>>(x, W, rows, hidden, cnt);
    offset_kernel<<<NB / 8, 512, 0, stream>>>(cnt, woff, gcount);
    scan_kernel<<<1, 64, 0, stream>>>(gcount, bbase);
    sort_scatter_kernel<<<NB, 1024, 0, stream>>>(rows, cols, ev, cnt, woff, bbase, csr);
    sortgather_kernel<<<NB, 1024, 0, stream>>>(hidden, csr, bbase, out);
}